// Round 8
// baseline (294.801 us; speedup 1.0000x reference)
//
#include <hip/hip_runtime.h>
#include <math.h>

// SoftRasterizer: B=1, V=5023, F=10000, IMG=128.
// R8: global counting-sort permutation by zub (deterministic: bucket desc,
// fid asc; 1024 buckets) replaces the 97us bitonic k_sort. k_main is binless:
// each (tile,seg) block strides the globally z-sorted face list and breaks on
// the absorbing state (__all(pr==0 & bucket_ub <= m-1.3e-4) => bit-exact
// no-op tail). Eval arithmetic identical to R6/R7 (passed, absmax 3.9e-3).

#define NFACE 10000
#define IMG   128
#define P_TOT (IMG*IMG)
#define FSTR  40               // floats per face record
#define NTILE 64               // 8x8 tiles of 16x16 px
#define NB    1024             // z buckets
#define CH    256              // faces per sort chunk
#define NCH   40               // ceil(NFACE/CH)
#define Z_LO  0.85f
#define Z_W   (0.12f/1024.0f)  // bucket width

__device__ __forceinline__ float rcp_nr(float x) {
    float r = __builtin_amdgcn_rcpf(x);
    r = r * __builtin_fmaf(-x, r, 2.0f);   // one Newton step -> ~1 ulp
    return r;
}

__device__ __forceinline__ float segd(float px, float py, float ax, float ay,
                                      float bx, float by, float il) {
    float dx = px - ax, dy = py - ay;
    float ex = bx - ax, ey = by - ay;
    float t = (dx * ex + dy * ey) * il;
    t = fminf(fmaxf(t, 0.0f), 1.0f);
    float rx = dx - t * ex, ry = dy - t * ey;
    return rx * rx + ry * ry;
}

__device__ __forceinline__ float rfl_f(float x) {
    return __uint_as_float(__builtin_amdgcn_readfirstlane(__float_as_uint(x)));
}

__device__ __forceinline__ int zbucket(float zub) {
    int b = (int)((zub - Z_LO) * (1.0f / Z_W));
    return min(max(b, 0), NB - 1);
}

// record: 0..5 xy012 | 6..8 1/z | 9..12 a0 b0 a1 b1 | 13 detp | 14..16 margins
// 17..19 il | 20..23 bbox | 24 mult | 25..33 tex | 34 rdetp | 35 zpn_ub
// 36..38 rg0..2 | 39 pad
__global__ __launch_bounds__(256) void k_pre(const float* __restrict__ v,
                                             const int* __restrict__ fc,
                                             const float* __restrict__ at,
                                             float* __restrict__ fb) {
    int f = blockIdx.x * 256 + threadIdx.x;
    if (f >= NFACE) return;
    int i0 = fc[3 * f], i1 = fc[3 * f + 1], i2 = fc[3 * f + 2];
    float x0 = -v[3 * i0], y0 = v[3 * i0 + 1], z0 = v[3 * i0 + 2];
    float x1 = -v[3 * i1], y1 = v[3 * i1 + 1], z1 = v[3 * i1 + 2];
    float x2 = -v[3 * i2], y2 = v[3 * i2 + 1], z2 = v[3 * i2 + 2];

    float det = (y1 - y2) * (x0 - x2) + (x2 - x1) * (y0 - y2);
    if (fabsf(det) < 1e-10f) det = (det < 0.0f) ? -1e-10f : 1e-10f;
    float a0 = y1 - y2, b0 = x2 - x1, a1 = y2 - y0, b1 = x0 - x2, detp = det;
    if (det < 0.0f) { detp = -det; a0 = -a0; b0 = -b0; a1 = -a1; b1 = -b1; }

    float a2 = a0 + a1, b2 = b0 + b1;
    float g0 = fmaxf(sqrtf(a0 * a0 + b0 * b0), 1e-12f);
    float g1 = fmaxf(sqrtf(a1 * a1 + b1 * b1), 1e-12f);
    float g2 = fmaxf(sqrtf(a2 * a2 + b2 * b2), 1e-12f);
    const float MARG = 3e-5f, AG = 1e-9f;
    float m0 = -(MARG * g0 + AG), m1 = -(MARG * g1 + AG), m2 = -(MARG * g2 + AG);

    float e01x = x1 - x0, e01y = y1 - y0;
    float e12x = x2 - x1, e12y = y2 - y1;
    float e20x = x0 - x2, e20y = y0 - y2;
    float il01 = 1.0f / fmaxf(e01x * e01x + e01y * e01y, 1e-12f);
    float il12 = 1.0f / fmaxf(e12x * e12x + e12y * e12y, 1e-12f);
    float il20 = 1.0f / fmaxf(e20x * e20x + e20y * e20y, 1e-12f);

    const float BM = 2e-5f;
    float bxmin = fminf(fminf(x0, x1), x2) - BM, bxmax = fmaxf(fmaxf(x0, x1), x2) + BM;
    float bymin = fminf(fminf(y0, y1), y2) - BM, bymax = fmaxf(fmaxf(y0, y1), y2) + BM;

    int mult = (((y2 - y0) * (x1 - x0)) < ((y1 - y0) * (x2 - x0)))
             + (((y0 - y2) * (x1 - x2)) < ((y1 - y2) * (x0 - x2)));

    float zmin = fminf(fminf(z0, z1), z2);
    float zpn_ub = (100.0f - zmin) / 99.0f + 2e-6f;   // safe upper bound on zpn

    float* F = fb + (size_t)f * FSTR;
    F[0] = x0; F[1] = y0; F[2] = x1; F[3] = y1; F[4] = x2; F[5] = y2;
    F[6] = 1.0f / z0; F[7] = 1.0f / z1; F[8] = 1.0f / z2;
    F[9] = a0; F[10] = b0; F[11] = a1; F[12] = b1; F[13] = detp;
    F[14] = m0; F[15] = m1; F[16] = m2;
    F[17] = il01; F[18] = il12; F[19] = il20;
    F[20] = bxmin; F[21] = bxmax; F[22] = bymin; F[23] = bymax;
    F[24] = (float)mult;
#pragma unroll
    for (int k = 0; k < 9; k++) F[25 + k] = at[(size_t)f * 9 + k];
    F[34] = 1.0f / detp;
    F[35] = zpn_ub;
    F[36] = 1.0f / g0; F[37] = 1.0f / g1; F[38] = 1.0f / g2;
    F[39] = 0.0f;
}

// per-chunk bucket histograms (LDS atomics -> deterministic counts)
__global__ __launch_bounds__(256) void k_hist(const float* __restrict__ fb,
                                              int* __restrict__ hist) {
    __shared__ int lh[NB];
    int c = blockIdx.x, tid = threadIdx.x;
    for (int j = tid; j < NB; j += 256) lh[j] = 0;
    __syncthreads();
    int f = c * CH + tid;
    if (f < NFACE) {
        int b = zbucket(fb[(size_t)f * FSTR + 35]);
        atomicAdd(&lh[b], 1);
    }
    __syncthreads();
    for (int j = tid; j < NB; j += 256) hist[c * NB + j] = lh[j];
}

// one block: suffix-sum over buckets (desc order) + per-chunk bases in-place
__global__ __launch_bounds__(1024) void k_scan(int* __restrict__ hist) {
    __shared__ int a[NB];
    int t = threadIdx.x;
    int tot = 0;
    for (int c = 0; c < NCH; c++) tot += hist[c * NB + t];
    a[t] = tot;
    for (int off = 1; off < NB; off <<= 1) {
        __syncthreads();
        int v = a[t] + ((t + off < NB) ? a[t + off] : 0);
        __syncthreads();
        a[t] = v;
    }
    int base = a[t] - tot;          // sum of counts for buckets > t
    int r = base;
    for (int c = 0; c < NCH; c++) {
        int h = hist[c * NB + t];
        hist[c * NB + t] = r;
        r += h;
    }
}

// scatter: stable rank within chunk via LDS broadcast loop
__global__ __launch_bounds__(256) void k_scatter(const float* __restrict__ fb,
                                                 const int* __restrict__ hist,
                                                 int* __restrict__ perm,
                                                 float* __restrict__ zubq) {
    __shared__ int sb[CH];
    int c = blockIdx.x, tid = threadIdx.x;
    int f = c * CH + tid;
    bool valid = (f < NFACE);
    int b = valid ? zbucket(fb[(size_t)f * FSTR + 35]) : -1;
    sb[tid] = b;
    __syncthreads();
    if (valid) {
        int rank = 0;
        for (int j = 0; j < CH; j++) {
            int v = sb[j];                       // LDS broadcast
            rank += (j < tid && v == b) ? 1 : 0;
        }
        int pos = hist[c * NB + b] + rank;
        perm[pos] = f;
        zubq[pos] = Z_LO + (float)(b + 1) * Z_W + 1e-7f;   // bucket upper bound
    }
}

__global__ __launch_bounds__(256) void k_main(const float* __restrict__ fb,
                                              const int* __restrict__ perm,
                                              const float* __restrict__ zubq,
                                              float* __restrict__ part) {
    int t = blockIdx.x;
    int seg = blockIdx.y, S = gridDim.y;

    int tid = threadIdx.x;
    int tx = t & 7, ty = t >> 3;
    int col = tx * 16 + (tid & 15);
    int row = ty * 16 + (tid >> 4);
    float px = (float)(2 * col + 1 - IMG) / (float)IMG;
    float py = (float)(2 * (IMG - 1 - row) + 1 - IMG) / (float)IMG;

    float m = -__builtin_inff();
    float s = 0.0f, ca = 0.0f, cb = 0.0f, cc = 0.0f, pr = 1.0f;

    const float NEAR_T = 4.3e-3f;   // lb > this => sigmoid rounds to 1.0f exactly
    const float ZM = 1.3e-4f;       // exp((zpn-m)*1e6) == 0.0f beyond this gap

    int i = seg;
    while (i < NFACE) {
        float zubi = rfl_f(zubq[i]);
        // absorbing state: list is zub-desc => rest is a bit-exact no-op
        if (__all((pr == 0.0f) & (zubi <= m - ZM))) break;
        int fj = __builtin_amdgcn_readfirstlane(perm[i]);
        i += S;
        const float* F = fb + (size_t)fj * FSTR;

        bool inbox = (px >= F[20]) & (px <= F[21]) & (py >= F[22]) & (py <= F[23]);
        if (!__any(inbox)) continue;

        float x2 = F[4], y2 = F[5];
        float dx2 = px - x2, dy2 = py - y2;
        float num0 = F[9] * dx2 + F[10] * dy2;
        float num1 = F[11] * dx2 + F[12] * dy2;
        float detp = F[13];
        float num2 = detp - num0 - num1;
        bool maybe = inbox & (num0 >= F[14]) & (num1 >= F[15]) & (num2 >= F[16]);
        if (!__any(maybe)) continue;

        bool inside = (num0 >= 0.0f) & (num1 >= 0.0f) & (num2 >= 0.0f);
        bool inside_l = inside & inbox;

        float lin0 = num0 * F[36];
        float lin1 = num1 * F[37];
        float lin2 = num2 * F[38];
        float lbmin = fminf(fminf(lin0, lin1), lin2);

        bool outNear = maybe & (!inside);            // within margins, outside
        bool nearIn  = inside_l & (lbmin < NEAR_T);  // inside, near an edge
        bool anyNear = __any(nearIn | outNear);

        float dis = 1e9f;
        float Dp;
        if (anyNear) {
            bool needAll = __any(outNear);
            float x0 = F[0], y0 = F[1], x1 = F[2], y1 = F[3];
            float d01 = 1e9f, d12 = 1e9f, d20 = 1e9f;
            if (needAll | __any(inside_l & (lin2 < NEAR_T)))
                d01 = segd(px, py, x0, y0, x1, y1, F[17]);
            if (needAll | __any(inside_l & (lin0 < NEAR_T)))
                d12 = segd(px, py, x1, y1, x2, y2, F[18]);
            if (needAll | __any(inside_l & (lin1 < NEAR_T)))
                d20 = segd(px, py, x2, y2, x0, y0, F[19]);
            dis = fminf(fminf(d01, d12), d20);

            float q = dis * 1e6f;
            float xs_ = inside ? q : -q;
            float tt = __expf(-fabsf(xs_));
            float Dpn = (xs_ >= 0.0f ? 1.0f : tt) * rcp_nr(1.0f + tt);
            bool nearl = nearIn | outNear;
            Dp = nearl ? Dpn : (inside_l ? 1.0f : 0.0f);
        } else {
            Dp = inside_l ? 1.0f : 0.0f;
        }

        bool contrib = inside_l | (outNear & (dis < 1e-10f));
        Dp = contrib ? Dp : 0.0f;
        float omd = 1.0f - Dp;
        pr *= contrib ? (omd * omd) : 1.0f;   // both winding copies

        float multf = F[24];
        bool doz = contrib & (multf > 0.0f);
        if (__any(doz & (zubi > m - ZM))) {
            float rdetp = F[34];
            float w0 = num0 * rdetp;
            float w1 = num1 * rdetp;
            float c0 = fminf(fmaxf(w0, 0.0f), 1.0f);
            float c1 = fminf(fmaxf(w1, 0.0f), 1.0f);
            float c2 = fminf(fmaxf(1.0f - w0 - w1, 0.0f), 1.0f);
            float csum = fmaxf(c0 + c1 + c2, 1e-5f);
            float rcs = rcp_nr(csum);
            c0 *= rcs; c1 *= rcs; c2 *= rcs;
            float zpi = c0 * F[6] + c1 * F[7] + c2 * F[8];
            if (fabsf(zpi) < 1e-12f) zpi = 1e-12f;
            float zp = rcp_nr(zpi);
            if (doz & (zp >= 1.0f) & (zp <= 100.0f)) {
                float zpn = (100.0f - zp) / 99.0f;   // keep IEEE: critical
                if (zpn > m) {
                    float scl = __expf((m - zpn) * 1e6f);
                    s *= scl; ca *= scl; cb *= scl; cc *= scl;
                    m = zpn;
                }
                float arg = (zpn - m) * 1e6f;
                if (arg > -110.0f) {
                    float e = __expf(arg) * Dp * multf;
                    float col0 = c0 * F[25] + c1 * F[28] + c2 * F[31];
                    float col1 = c0 * F[26] + c1 * F[29] + c2 * F[32];
                    float col2 = c0 * F[27] + c1 * F[30] + c2 * F[33];
                    s += e; ca += e * col0; cb += e * col1; cc += e * col2;
                }
            }
        }
    }

    size_t pb = ((size_t)t * gridDim.y + seg) * 6 * 256;
    part[pb + 0 * 256 + tid] = m;
    part[pb + 1 * 256 + tid] = s;
    part[pb + 2 * 256 + tid] = ca;
    part[pb + 3 * 256 + tid] = cb;
    part[pb + 4 * 256 + tid] = cc;
    part[pb + 5 * 256 + tid] = pr;
}

__global__ __launch_bounds__(256) void k_reduce(const float* __restrict__ part,
                                                float* __restrict__ out,
                                                int S) {
    int t = blockIdx.x;
    int q = threadIdx.x;
    int tx = t & 7, ty = t >> 3;
    int col = tx * 16 + (q & 15);
    int row = ty * 16 + (q >> 4);
    int p = row * IMG + col;
    int start = t * S;

    float m = 0.001f;   // BG_EPS
    for (int sgi = 0; sgi < S; sgi++)
        m = fmaxf(m, part[((size_t)(start + sgi) * 6 + 0) * 256 + q]);
    float sum = __expf((0.001f - m) * 1e6f);   // background term (s0=1)
    float a = 0.0f, b = 0.0f, c = 0.0f, pr = 1.0f;
    for (int sgi = 0; sgi < S; sgi++) {
        const float* r = part + ((size_t)(start + sgi) * 6) * 256;
        float w = __expf((r[0 * 256 + q] - m) * 1e6f);   // exp(-inf)=0 for empty
        pr *= r[5 * 256 + q];
        if (__any(w != 0.0f)) {
            sum += r[1 * 256 + q] * w;
            a += r[2 * 256 + q] * w;
            b += r[3 * 256 + q] * w;
            c += r[4 * 256 + q] * w;
        }
    }
    out[0 * P_TOT + p] = a / sum;
    out[1 * P_TOT + p] = b / sum;
    out[2 * P_TOT + p] = c / sum;
    out[3 * P_TOT + p] = 1.0f - pr;
}

extern "C" void kernel_launch(void* const* d_in, const int* in_sizes, int n_in,
                              void* d_out, int out_size, void* d_ws, size_t ws_size,
                              hipStream_t stream) {
    const float* verts = (const float*)d_in[0];
    const int*   faces = (const int*)d_in[1];
    const float* attrs = (const float*)d_in[2];
    float* out = (float*)d_out;
    float* ws  = (float*)d_ws;

    float* fb   = ws;                                   // NFACE*FSTR = 400K floats
    int*   hist = (int*)(fb + (size_t)NFACE * FSTR);    // NCH*NB = 40960
    int*   perm = hist + NCH * NB;                      // 10000
    float* zubq = (float*)(perm + NFACE);               // 10000
    float* part = zubq + NFACE;

    size_t used_f = (size_t)NFACE * FSTR + NCH * NB + 2 * NFACE;
    long   rem_f  = (long)(ws_size / 4) - (long)used_f;
    int S = (int)(rem_f / (NTILE * 6 * 256));
    if (S > 40) S = 40;
    if (S < 4)  S = 4;

    k_pre<<<(NFACE + 255) / 256, 256, 0, stream>>>(verts, faces, attrs, fb);
    k_hist<<<NCH, 256, 0, stream>>>(fb, hist);
    k_scan<<<1, 1024, 0, stream>>>(hist);
    k_scatter<<<NCH, 256, 0, stream>>>(fb, hist, perm, zubq);
    k_main<<<dim3(NTILE, S), 256, 0, stream>>>(fb, perm, zubq, part);
    k_reduce<<<NTILE, 256, 0, stream>>>(part, out, S);
}

// Round 9
// 197.994 us; speedup vs baseline: 1.4889x; 1.4889x over previous
//
#include <hip/hip_runtime.h>
#include <math.h>

// SoftRasterizer: B=1, V=5023, F=10000, IMG=128.
// R9 = R8's cheap global counting z-sort + R7's per-tile binning (tight test,
// walked in perm order so tile lists are zub-descending) + R5's
// work-proportional block map + absorbing break + scalar-pair prefetch.
// Eval arithmetic identical to R6/R7/R8 (all passed, absmax 3.9e-3).

#define NFACE 10000
#define IMG   128
#define P_TOT (IMG*IMG)
#define FSTR  40               // floats per face record
#define NTILE 64               // 8x8 tiles of 16x16 px
#define CAP   10000            // per-tile list capacity
#define BMAX  2560             // max k_main blocks
#define NB    1024             // z buckets
#define CH    256              // faces per sort chunk
#define NCH   40               // ceil(NFACE/CH)
#define Z_LO  0.85f
#define Z_W   (0.12f/1024.0f)  // bucket width

__device__ __forceinline__ float rcp_nr(float x) {
    float r = __builtin_amdgcn_rcpf(x);
    r = r * __builtin_fmaf(-x, r, 2.0f);   // one Newton step -> ~1 ulp
    return r;
}

__device__ __forceinline__ float segd(float px, float py, float ax, float ay,
                                      float bx, float by, float il) {
    float dx = px - ax, dy = py - ay;
    float ex = bx - ax, ey = by - ay;
    float t = (dx * ex + dy * ey) * il;
    t = fminf(fmaxf(t, 0.0f), 1.0f);
    float rx = dx - t * ex, ry = dy - t * ey;
    return rx * rx + ry * ry;
}

__device__ __forceinline__ float rfl_f(float x) {
    return __uint_as_float(__builtin_amdgcn_readfirstlane(__float_as_uint(x)));
}

__device__ __forceinline__ int zbucket(float zub) {
    int b = (int)((zub - Z_LO) * (1.0f / Z_W));
    return min(max(b, 0), NB - 1);
}

// record: 0..5 xy012 | 6..8 1/z | 9..12 a0 b0 a1 b1 | 13 detp | 14..16 margins
// 17..19 il | 20..23 bbox | 24 mult | 25..33 tex | 34 rdetp | 35 zpn_ub
// 36..38 rg0..2 | 39 pad
__global__ __launch_bounds__(256) void k_pre(const float* __restrict__ v,
                                             const int* __restrict__ fc,
                                             const float* __restrict__ at,
                                             float* __restrict__ fb) {
    int f = blockIdx.x * 256 + threadIdx.x;
    if (f >= NFACE) return;
    int i0 = fc[3 * f], i1 = fc[3 * f + 1], i2 = fc[3 * f + 2];
    float x0 = -v[3 * i0], y0 = v[3 * i0 + 1], z0 = v[3 * i0 + 2];
    float x1 = -v[3 * i1], y1 = v[3 * i1 + 1], z1 = v[3 * i1 + 2];
    float x2 = -v[3 * i2], y2 = v[3 * i2 + 1], z2 = v[3 * i2 + 2];

    float det = (y1 - y2) * (x0 - x2) + (x2 - x1) * (y0 - y2);
    if (fabsf(det) < 1e-10f) det = (det < 0.0f) ? -1e-10f : 1e-10f;
    float a0 = y1 - y2, b0 = x2 - x1, a1 = y2 - y0, b1 = x0 - x2, detp = det;
    if (det < 0.0f) { detp = -det; a0 = -a0; b0 = -b0; a1 = -a1; b1 = -b1; }

    float a2 = a0 + a1, b2 = b0 + b1;
    float g0 = fmaxf(sqrtf(a0 * a0 + b0 * b0), 1e-12f);
    float g1 = fmaxf(sqrtf(a1 * a1 + b1 * b1), 1e-12f);
    float g2 = fmaxf(sqrtf(a2 * a2 + b2 * b2), 1e-12f);
    const float MARG = 3e-5f, AG = 1e-9f;
    float m0 = -(MARG * g0 + AG), m1 = -(MARG * g1 + AG), m2 = -(MARG * g2 + AG);

    float e01x = x1 - x0, e01y = y1 - y0;
    float e12x = x2 - x1, e12y = y2 - y1;
    float e20x = x0 - x2, e20y = y0 - y2;
    float il01 = 1.0f / fmaxf(e01x * e01x + e01y * e01y, 1e-12f);
    float il12 = 1.0f / fmaxf(e12x * e12x + e12y * e12y, 1e-12f);
    float il20 = 1.0f / fmaxf(e20x * e20x + e20y * e20y, 1e-12f);

    const float BM = 2e-5f;
    float bxmin = fminf(fminf(x0, x1), x2) - BM, bxmax = fmaxf(fmaxf(x0, x1), x2) + BM;
    float bymin = fminf(fminf(y0, y1), y2) - BM, bymax = fmaxf(fmaxf(y0, y1), y2) + BM;

    int mult = (((y2 - y0) * (x1 - x0)) < ((y1 - y0) * (x2 - x0)))
             + (((y0 - y2) * (x1 - x2)) < ((y1 - y2) * (x0 - x2)));

    float zmin = fminf(fminf(z0, z1), z2);
    float zpn_ub = (100.0f - zmin) / 99.0f + 2e-6f;   // safe upper bound on zpn

    float* F = fb + (size_t)f * FSTR;
    F[0] = x0; F[1] = y0; F[2] = x1; F[3] = y1; F[4] = x2; F[5] = y2;
    F[6] = 1.0f / z0; F[7] = 1.0f / z1; F[8] = 1.0f / z2;
    F[9] = a0; F[10] = b0; F[11] = a1; F[12] = b1; F[13] = detp;
    F[14] = m0; F[15] = m1; F[16] = m2;
    F[17] = il01; F[18] = il12; F[19] = il20;
    F[20] = bxmin; F[21] = bxmax; F[22] = bymin; F[23] = bymax;
    F[24] = (float)mult;
#pragma unroll
    for (int k = 0; k < 9; k++) F[25 + k] = at[(size_t)f * 9 + k];
    F[34] = 1.0f / detp;
    F[35] = zpn_ub;
    F[36] = 1.0f / g0; F[37] = 1.0f / g1; F[38] = 1.0f / g2;
    F[39] = 0.0f;
}

// per-chunk bucket histograms (LDS atomics -> deterministic counts)
__global__ __launch_bounds__(256) void k_hist(const float* __restrict__ fb,
                                              int* __restrict__ hist) {
    __shared__ int lh[NB];
    int c = blockIdx.x, tid = threadIdx.x;
    for (int j = tid; j < NB; j += 256) lh[j] = 0;
    __syncthreads();
    int f = c * CH + tid;
    if (f < NFACE) {
        int b = zbucket(fb[(size_t)f * FSTR + 35]);
        atomicAdd(&lh[b], 1);
    }
    __syncthreads();
    for (int j = tid; j < NB; j += 256) hist[c * NB + j] = lh[j];
}

// one block: suffix-sum over buckets (desc order) + per-chunk bases in-place
__global__ __launch_bounds__(1024) void k_scan(int* __restrict__ hist) {
    __shared__ int a[NB];
    int t = threadIdx.x;
    int tot = 0;
    for (int c = 0; c < NCH; c++) tot += hist[c * NB + t];
    a[t] = tot;
    for (int off = 1; off < NB; off <<= 1) {
        __syncthreads();
        int v = a[t] + ((t + off < NB) ? a[t + off] : 0);
        __syncthreads();
        a[t] = v;
    }
    int base = a[t] - tot;          // sum of counts for buckets > t
    int r = base;
    for (int c = 0; c < NCH; c++) {
        int h = hist[c * NB + t];
        hist[c * NB + t] = r;
        r += h;
    }
}

// scatter: stable rank within chunk via LDS broadcast loop
__global__ __launch_bounds__(256) void k_scatter(const float* __restrict__ fb,
                                                 const int* __restrict__ hist,
                                                 int* __restrict__ perm,
                                                 float* __restrict__ zubq) {
    __shared__ int sb[CH];
    int c = blockIdx.x, tid = threadIdx.x;
    int f = c * CH + tid;
    bool valid = (f < NFACE);
    int b = valid ? zbucket(fb[(size_t)f * FSTR + 35]) : -1;
    sb[tid] = b;
    __syncthreads();
    if (valid) {
        int rank = 0;
        for (int j = 0; j < CH; j++) {
            int v = sb[j];                       // LDS broadcast
            rank += (j < tid && v == b) ? 1 : 0;
        }
        int pos = hist[c * NB + b] + rank;
        perm[pos] = f;
        zubq[pos] = Z_LO + (float)(b + 1) * Z_W + 1e-7f;   // bucket upper bound
    }
}

// one block per tile; walks perm order (z-desc) -> tile lists stay z-desc.
// Tight test: bbox overlap AND per-edge corner-max(num_k) >= margin_k.
__global__ __launch_bounds__(256) void k_bin(const float* __restrict__ fb,
                                             const int* __restrict__ perm,
                                             const float* __restrict__ zubq,
                                             int* __restrict__ lid,
                                             float* __restrict__ lz,
                                             int* __restrict__ counts) {
    int t = blockIdx.x;
    int tid = threadIdx.x, wv = tid >> 6, lane = tid & 63;
    int tx = t & 7, ty = t >> 3;
    float x_lo = (float)(2 * (tx * 16) + 1 - IMG) / (float)IMG;
    float x_hi = (float)(2 * (tx * 16 + 15) + 1 - IMG) / (float)IMG;
    float y_hi = (float)(127 - 2 * (ty * 16)) / (float)IMG;
    float y_lo = (float)(127 - 2 * (ty * 16 + 15)) / (float)IMG;
    float cx = 0.5f * (x_lo + x_hi), hx = 0.5f * (x_hi - x_lo);
    float cy = 0.5f * (y_lo + y_hi), hy = 0.5f * (y_hi - y_lo);

    __shared__ int wc[4];
    int cnt = 0;
    for (int base = 0; base < NFACE; base += 256) {
        int j = base + tid;
        bool ov = false;
        int f = 0;
        float zub = 0.0f;
        if (j < NFACE) {
            f = perm[j];
            const float* F = fb + (size_t)f * FSTR;
            ov = (F[20] <= x_hi) & (F[21] >= x_lo) & (F[22] <= y_hi) & (F[23] >= y_lo);
            if (ov) {
                float dx = cx - F[4], dy = cy - F[5];
                float A0 = F[9], B0 = F[10], A1 = F[11], B1 = F[12];
                float mx0 = A0 * dx + B0 * dy + fabsf(A0) * hx + fabsf(B0) * hy;
                float mx1 = A1 * dx + B1 * dy + fabsf(A1) * hx + fabsf(B1) * hy;
                float A2 = -(A0 + A1), B2 = -(B0 + B1);
                float mx2 = F[13] + A2 * dx + B2 * dy + fabsf(A2) * hx + fabsf(B2) * hy;
                ov = (mx0 >= F[14]) & (mx1 >= F[15]) & (mx2 >= F[16]);
                zub = zubq[j];
            }
        }
        unsigned long long mask = __ballot(ov);
        if (lane == 0) wc[wv] = __popcll(mask);
        __syncthreads();
        int off = cnt;
        for (int w = 0; w < 4; ++w) {
            if (w < wv) off += wc[w];
        }
        if (ov) {
            int pos = off + __popcll(mask & ((1ull << lane) - 1ull));
            lid[(size_t)t * CAP + pos] = f;
            lz[(size_t)t * CAP + pos] = zub;
        }
        cnt += wc[0] + wc[1] + wc[2] + wc[3];
        __syncthreads();
    }
    if (tid == 0) counts[t] = cnt;
}

// one wave: S_t ~ len_t (sum <= B), prefix starts, block->(tile,seg) map
__global__ __launch_bounds__(64) void k_map(const int* __restrict__ counts,
                                            int* __restrict__ map,
                                            int* __restrict__ starts,
                                            int* __restrict__ segs,
                                            int B) {
    int lane = threadIdx.x;              // 0..63, one wave, 64 tiles
    int len = counts[lane];
    int tot = len;
    for (int o = 32; o > 0; o >>= 1) tot += __shfl_down(tot, o);
    tot = __shfl(tot, 0);
    int St = max(1, (int)(((long long)len * (long long)(B - NTILE)) /
                          (long long)max(tot, 1)));
    __shared__ int sS[64], sP[64];
    sS[lane] = St;
    __syncthreads();
    if (lane == 0) {
        int acc = 0;
        for (int t = 0; t < 64; ++t) { sP[t] = acc; acc += sS[t]; }
    }
    __syncthreads();
    for (int i = lane; i < B; i += 64) map[i] = -1;
    __syncthreads();
    int st = sP[lane];
    starts[lane] = st;
    segs[lane] = St;
    for (int s = 0; s < St; ++s) map[st + s] = (lane << 16) | s;
}

__global__ __launch_bounds__(256) void k_main(const float* __restrict__ fb,
                                              const int* __restrict__ lid,
                                              const float* __restrict__ lz,
                                              const int* __restrict__ counts,
                                              const int* __restrict__ map,
                                              const int* __restrict__ segs,
                                              float* __restrict__ part) {
    int bid = blockIdx.x;
    int mv = map[bid];
    if (mv < 0) return;
    int t = mv >> 16, seg = mv & 0xffff;
    int S = segs[t];
    int len = counts[t];

    int tid = threadIdx.x;
    int tx = t & 7, ty = t >> 3;
    int col = tx * 16 + (tid & 15);
    int row = ty * 16 + (tid >> 4);
    float px = (float)(2 * col + 1 - IMG) / (float)IMG;
    float py = (float)(2 * (IMG - 1 - row) + 1 - IMG) / (float)IMG;

    const int*   plid = lid + (size_t)t * CAP;
    const float* plz  = lz  + (size_t)t * CAP;

    float m = -__builtin_inff();
    float s = 0.0f, ca = 0.0f, cb = 0.0f, cc = 0.0f, pr = 1.0f;

    const float NEAR_T = 4.3e-3f;   // lb > this => sigmoid rounds to 1.0f exactly
    const float ZM = 1.3e-4f;       // exp((zpn-m)*1e6) == 0.0f beyond this gap

    int i = seg;
    float zubi = 0.0f; int fj = 0;
    if (i < len) { zubi = rfl_f(plz[i]); fj = __builtin_amdgcn_readfirstlane(plid[i]); }
    while (i < len) {
        // absorbing state: list is zub-desc => rest is a bit-exact no-op
        if (__all((pr == 0.0f) & (zubi <= m - ZM))) break;
        int inext = i + S;
        float zubn = 0.0f; int fn = 0;
        if (inext < len) {                    // prefetch next pair
            zubn = rfl_f(plz[inext]);
            fn = __builtin_amdgcn_readfirstlane(plid[inext]);
        }
        const float* F = fb + (size_t)fj * FSTR;
        float zcur = zubi;
        i = inext; zubi = zubn; fj = fn;

        bool inbox = (px >= F[20]) & (px <= F[21]) & (py >= F[22]) & (py <= F[23]);
        if (!__any(inbox)) continue;

        float x2 = F[4], y2 = F[5];
        float dx2 = px - x2, dy2 = py - y2;
        float num0 = F[9] * dx2 + F[10] * dy2;
        float num1 = F[11] * dx2 + F[12] * dy2;
        float detp = F[13];
        float num2 = detp - num0 - num1;
        bool maybe = inbox & (num0 >= F[14]) & (num1 >= F[15]) & (num2 >= F[16]);
        if (!__any(maybe)) continue;

        bool inside = (num0 >= 0.0f) & (num1 >= 0.0f) & (num2 >= 0.0f);
        bool inside_l = inside & inbox;

        float lin0 = num0 * F[36];
        float lin1 = num1 * F[37];
        float lin2 = num2 * F[38];
        float lbmin = fminf(fminf(lin0, lin1), lin2);

        bool outNear = maybe & (!inside);            // within margins, outside
        bool nearIn  = inside_l & (lbmin < NEAR_T);  // inside, near an edge
        bool anyNear = __any(nearIn | outNear);

        float dis = 1e9f;
        float Dp;
        if (anyNear) {
            bool needAll = __any(outNear);
            float x0 = F[0], y0 = F[1], x1 = F[2], y1 = F[3];
            float d01 = 1e9f, d12 = 1e9f, d20 = 1e9f;
            if (needAll | __any(inside_l & (lin2 < NEAR_T)))
                d01 = segd(px, py, x0, y0, x1, y1, F[17]);
            if (needAll | __any(inside_l & (lin0 < NEAR_T)))
                d12 = segd(px, py, x1, y1, x2, y2, F[18]);
            if (needAll | __any(inside_l & (lin1 < NEAR_T)))
                d20 = segd(px, py, x2, y2, x0, y0, F[19]);
            dis = fminf(fminf(d01, d12), d20);

            float q = dis * 1e6f;
            float xs_ = inside ? q : -q;
            float tt = __expf(-fabsf(xs_));
            float Dpn = (xs_ >= 0.0f ? 1.0f : tt) * rcp_nr(1.0f + tt);
            bool nearl = nearIn | outNear;
            Dp = nearl ? Dpn : (inside_l ? 1.0f : 0.0f);
        } else {
            Dp = inside_l ? 1.0f : 0.0f;
        }

        bool contrib = inside_l | (outNear & (dis < 1e-10f));
        Dp = contrib ? Dp : 0.0f;
        float omd = 1.0f - Dp;
        pr *= contrib ? (omd * omd) : 1.0f;   // both winding copies

        float multf = F[24];
        bool doz = contrib & (multf > 0.0f);
        if (__any(doz & (zcur > m - ZM))) {
            float rdetp = F[34];
            float w0 = num0 * rdetp;
            float w1 = num1 * rdetp;
            float c0 = fminf(fmaxf(w0, 0.0f), 1.0f);
            float c1 = fminf(fmaxf(w1, 0.0f), 1.0f);
            float c2 = fminf(fmaxf(1.0f - w0 - w1, 0.0f), 1.0f);
            float csum = fmaxf(c0 + c1 + c2, 1e-5f);
            float rcs = rcp_nr(csum);
            c0 *= rcs; c1 *= rcs; c2 *= rcs;
            float zpi = c0 * F[6] + c1 * F[7] + c2 * F[8];
            if (fabsf(zpi) < 1e-12f) zpi = 1e-12f;
            float zp = rcp_nr(zpi);
            if (doz & (zp >= 1.0f) & (zp <= 100.0f)) {
                float zpn = (100.0f - zp) / 99.0f;   // keep IEEE: critical
                if (zpn > m) {
                    float scl = __expf((m - zpn) * 1e6f);
                    s *= scl; ca *= scl; cb *= scl; cc *= scl;
                    m = zpn;
                }
                float arg = (zpn - m) * 1e6f;
                if (arg > -110.0f) {
                    float e = __expf(arg) * Dp * multf;
                    float col0 = c0 * F[25] + c1 * F[28] + c2 * F[31];
                    float col1 = c0 * F[26] + c1 * F[29] + c2 * F[32];
                    float col2 = c0 * F[27] + c1 * F[30] + c2 * F[33];
                    s += e; ca += e * col0; cb += e * col1; cc += e * col2;
                }
            }
        }
    }

    size_t pb = (size_t)bid * 6 * 256;
    part[pb + 0 * 256 + tid] = m;
    part[pb + 1 * 256 + tid] = s;
    part[pb + 2 * 256 + tid] = ca;
    part[pb + 3 * 256 + tid] = cb;
    part[pb + 4 * 256 + tid] = cc;
    part[pb + 5 * 256 + tid] = pr;
}

__global__ __launch_bounds__(256) void k_reduce(const float* __restrict__ part,
                                                const int* __restrict__ starts,
                                                const int* __restrict__ segs,
                                                float* __restrict__ out) {
    int t = blockIdx.x;
    int q = threadIdx.x;
    int tx = t & 7, ty = t >> 3;
    int col = tx * 16 + (q & 15);
    int row = ty * 16 + (q >> 4);
    int p = row * IMG + col;
    int start = starts[t], S = segs[t];

    float m = 0.001f;   // BG_EPS
    for (int sgi = 0; sgi < S; sgi++)
        m = fmaxf(m, part[((size_t)(start + sgi) * 6 + 0) * 256 + q]);
    float sum = __expf((0.001f - m) * 1e6f);   // background term (s0=1)
    float a = 0.0f, b = 0.0f, c = 0.0f, pr = 1.0f;
    for (int sgi = 0; sgi < S; sgi++) {
        const float* r = part + ((size_t)(start + sgi) * 6) * 256;
        float w = __expf((r[0 * 256 + q] - m) * 1e6f);   // exp(-inf)=0 for empty
        pr *= r[5 * 256 + q];
        if (__any(w != 0.0f)) {
            sum += r[1 * 256 + q] * w;
            a += r[2 * 256 + q] * w;
            b += r[3 * 256 + q] * w;
            c += r[4 * 256 + q] * w;
        }
    }
    out[0 * P_TOT + p] = a / sum;
    out[1 * P_TOT + p] = b / sum;
    out[2 * P_TOT + p] = c / sum;
    out[3 * P_TOT + p] = 1.0f - pr;
}

extern "C" void kernel_launch(void* const* d_in, const int* in_sizes, int n_in,
                              void* d_out, int out_size, void* d_ws, size_t ws_size,
                              hipStream_t stream) {
    const float* verts = (const float*)d_in[0];
    const int*   faces = (const int*)d_in[1];
    const float* attrs = (const float*)d_in[2];
    float* out = (float*)d_out;
    float* ws  = (float*)d_ws;

    float* fb     = ws;                                   // 400k floats
    int*   hist   = (int*)(fb + (size_t)NFACE * FSTR);    // NCH*NB
    int*   perm   = hist + NCH * NB;                      // 10000
    float* zubq   = (float*)(perm + NFACE);               // 10000
    int*   lid    = (int*)(zubq + NFACE);                 // NTILE*CAP
    float* lz     = (float*)(lid + (size_t)NTILE * CAP);  // NTILE*CAP
    int*   counts = (int*)(lz + (size_t)NTILE * CAP);     // 64
    int*   map    = counts + NTILE;                       // BMAX
    int*   starts = map + BMAX;                           // 64
    int*   segsum = starts + NTILE;                       // 64
    float* part   = (float*)(segsum + NTILE);

    size_t used_f = (size_t)NFACE * FSTR + NCH * NB + 2 * NFACE
                  + 2 * (size_t)NTILE * CAP + NTILE + BMAX + 2 * NTILE;
    long   rem_f  = (long)(ws_size / 4) - (long)used_f;
    int B = (int)(rem_f / (6 * 256));
    if (B > BMAX) B = BMAX;
    if (B < 256)  B = 256;

    k_pre<<<(NFACE + 255) / 256, 256, 0, stream>>>(verts, faces, attrs, fb);
    k_hist<<<NCH, 256, 0, stream>>>(fb, hist);
    k_scan<<<1, 1024, 0, stream>>>(hist);
    k_scatter<<<NCH, 256, 0, stream>>>(fb, hist, perm, zubq);
    k_bin<<<NTILE, 256, 0, stream>>>(fb, perm, zubq, lid, lz, counts);
    k_map<<<1, 64, 0, stream>>>(counts, map, starts, segsum, B);
    k_main<<<B, 256, 0, stream>>>(fb, lid, lz, counts, map, segsum, part);
    k_reduce<<<NTILE, 256, 0, stream>>>(part, starts, segsum, out);
}

// Round 10
// 192.625 us; speedup vs baseline: 1.5304x; 1.0279x over previous
//
#include <hip/hip_runtime.h>
#include <math.h>

// SoftRasterizer: B=1, V=5023, F=10000, IMG=128.
// R10 = R9 (198us) with: physical z-desc reorder of face records (fb2) so
// k_bin scans linearly (was a 60us+ scattered gather via perm) and k_main
// indexes fb2 directly; k_pre+k_hist fused; k_scatter+reorder fused; k_main
// prefetches the 4-float4 record head one iteration ahead (light path never
// stalls on L2). Eval arithmetic bit-identical to R6-R9 (absmax 3.9e-3).
//
// fb2 record layout (40 floats):
//  0-3  bxmin bxmax bymin bymax     | light path, float4 #0
//  4-7  x2 y2 a0 b0                 | float4 #1
//  8-11 a1 b1 detp zub(bucket-ub)   | float4 #2
// 12-15 m0 m1 m2 mult               | float4 #3
// 16-19 x0 y0 x1 y1
// 20-23 il01 il12 il20 rdetp
// 24-29 rz0 rz1 rz2 rg0 rg1 rg2
// 30-38 tex[9]   39 pad

#define NFACE 10000
#define IMG   128
#define P_TOT (IMG*IMG)
#define FSTR  40
#define NTILE 64               // 8x8 tiles of 16x16 px
#define CAP   10000
#define BMAX  2560
#define NB    1024             // z buckets
#define CH    256
#define NCH   40               // ceil(NFACE/CH)
#define Z_LO  0.85f
#define Z_W   (0.12f/1024.0f)

__device__ __forceinline__ float rcp_nr(float x) {
    float r = __builtin_amdgcn_rcpf(x);
    r = r * __builtin_fmaf(-x, r, 2.0f);
    return r;
}

__device__ __forceinline__ float segd(float px, float py, float ax, float ay,
                                      float bx, float by, float il) {
    float dx = px - ax, dy = py - ay;
    float ex = bx - ax, ey = by - ay;
    float t = (dx * ex + dy * ey) * il;
    t = fminf(fmaxf(t, 0.0f), 1.0f);
    float rx = dx - t * ex, ry = dy - t * ey;
    return rx * rx + ry * ry;
}

__device__ __forceinline__ float rfl_f(float x) {
    return __uint_as_float(__builtin_amdgcn_readfirstlane(__float_as_uint(x)));
}

__device__ __forceinline__ int zbucket(float zub) {
    int b = (int)((zub - Z_LO) * (1.0f / Z_W));
    return min(max(b, 0), NB - 1);
}

// fused k_pre + k_hist: block c handles faces [c*256, c*256+255]
__global__ __launch_bounds__(256) void k_prehist(const float* __restrict__ v,
                                                 const int* __restrict__ fc,
                                                 const float* __restrict__ at,
                                                 float* __restrict__ fb,
                                                 int* __restrict__ hist) {
    __shared__ int lh[NB];
    int c = blockIdx.x, tid = threadIdx.x;
    for (int j = tid; j < NB; j += 256) lh[j] = 0;
    __syncthreads();

    int f = c * CH + tid;
    if (f < NFACE) {
        int i0 = fc[3 * f], i1 = fc[3 * f + 1], i2 = fc[3 * f + 2];
        float x0 = -v[3 * i0], y0 = v[3 * i0 + 1], z0 = v[3 * i0 + 2];
        float x1 = -v[3 * i1], y1 = v[3 * i1 + 1], z1 = v[3 * i1 + 2];
        float x2 = -v[3 * i2], y2 = v[3 * i2 + 1], z2 = v[3 * i2 + 2];

        float det = (y1 - y2) * (x0 - x2) + (x2 - x1) * (y0 - y2);
        if (fabsf(det) < 1e-10f) det = (det < 0.0f) ? -1e-10f : 1e-10f;
        float a0 = y1 - y2, b0 = x2 - x1, a1 = y2 - y0, b1 = x0 - x2, detp = det;
        if (det < 0.0f) { detp = -det; a0 = -a0; b0 = -b0; a1 = -a1; b1 = -b1; }

        float a2 = a0 + a1, b2 = b0 + b1;
        float g0 = fmaxf(sqrtf(a0 * a0 + b0 * b0), 1e-12f);
        float g1 = fmaxf(sqrtf(a1 * a1 + b1 * b1), 1e-12f);
        float g2 = fmaxf(sqrtf(a2 * a2 + b2 * b2), 1e-12f);
        const float MARG = 3e-5f, AG = 1e-9f;
        float m0 = -(MARG * g0 + AG), m1 = -(MARG * g1 + AG), m2 = -(MARG * g2 + AG);

        float e01x = x1 - x0, e01y = y1 - y0;
        float e12x = x2 - x1, e12y = y2 - y1;
        float e20x = x0 - x2, e20y = y0 - y2;
        float il01 = 1.0f / fmaxf(e01x * e01x + e01y * e01y, 1e-12f);
        float il12 = 1.0f / fmaxf(e12x * e12x + e12y * e12y, 1e-12f);
        float il20 = 1.0f / fmaxf(e20x * e20x + e20y * e20y, 1e-12f);

        const float BM = 2e-5f;
        float bxmin = fminf(fminf(x0, x1), x2) - BM, bxmax = fmaxf(fmaxf(x0, x1), x2) + BM;
        float bymin = fminf(fminf(y0, y1), y2) - BM, bymax = fmaxf(fmaxf(y0, y1), y2) + BM;

        int mult = (((y2 - y0) * (x1 - x0)) < ((y1 - y0) * (x2 - x0)))
                 + (((y0 - y2) * (x1 - x2)) < ((y1 - y2) * (x0 - x2)));

        float zmin = fminf(fminf(z0, z1), z2);
        float zub = (100.0f - zmin) / 99.0f + 2e-6f;

        float* F = fb + (size_t)f * FSTR;
        F[0] = bxmin; F[1] = bxmax; F[2] = bymin; F[3] = bymax;
        F[4] = x2; F[5] = y2; F[6] = a0; F[7] = b0;
        F[8] = a1; F[9] = b1; F[10] = detp; F[11] = zub;
        F[12] = m0; F[13] = m1; F[14] = m2; F[15] = (float)mult;
        F[16] = x0; F[17] = y0; F[18] = x1; F[19] = y1;
        F[20] = il01; F[21] = il12; F[22] = il20; F[23] = 1.0f / detp;
        F[24] = 1.0f / z0; F[25] = 1.0f / z1; F[26] = 1.0f / z2;
        F[27] = 1.0f / g0; F[28] = 1.0f / g1; F[29] = 1.0f / g2;
#pragma unroll
        for (int k = 0; k < 9; k++) F[30 + k] = at[(size_t)f * 9 + k];
        F[39] = 0.0f;

        atomicAdd(&lh[zbucket(zub)], 1);
    }
    __syncthreads();
    for (int j = tid; j < NB; j += 256) hist[c * NB + j] = lh[j];
}

// one block: suffix-sum over buckets (desc) + per-chunk bases in-place
__global__ __launch_bounds__(1024) void k_scan(int* __restrict__ hist) {
    __shared__ int a[NB];
    int t = threadIdx.x;
    int tot = 0;
    for (int c = 0; c < NCH; c++) tot += hist[c * NB + t];
    a[t] = tot;
    for (int off = 1; off < NB; off <<= 1) {
        __syncthreads();
        int v = a[t] + ((t + off < NB) ? a[t + off] : 0);
        __syncthreads();
        a[t] = v;
    }
    int r = a[t] - tot;
    for (int c = 0; c < NCH; c++) {
        int h = hist[c * NB + t];
        hist[c * NB + t] = r;
        r += h;
    }
}

// fused scatter + physical reorder: fb2[pos] = fb[f], zub := bucket upper bound
__global__ __launch_bounds__(256) void k_scatterre(const float* __restrict__ fb,
                                                   const int* __restrict__ hist,
                                                   float* __restrict__ fb2) {
    __shared__ int sb[CH];
    int c = blockIdx.x, tid = threadIdx.x;
    int f = c * CH + tid;
    bool valid = (f < NFACE);
    int b = valid ? zbucket(fb[(size_t)f * FSTR + 11]) : -1;
    sb[tid] = b;
    __syncthreads();
    if (valid) {
        int rank = 0;
        for (int j = 0; j < CH; j++) {
            int v2 = sb[j];
            rank += (j < tid && v2 == b) ? 1 : 0;
        }
        int pos = hist[c * NB + b] + rank;
        const float4* src = (const float4*)(fb + (size_t)f * FSTR);
        float4* dst = (float4*)(fb2 + (size_t)pos * FSTR);
#pragma unroll
        for (int k = 0; k < 10; k++) dst[k] = src[k];
        fb2[(size_t)pos * FSTR + 11] = Z_LO + (float)(b + 1) * Z_W + 1e-7f;
    }
}

// one block per tile; linear scan of z-desc fb2 -> tile lists stay z-desc.
__global__ __launch_bounds__(256) void k_bin(const float* __restrict__ fb2,
                                             int* __restrict__ lid,
                                             float* __restrict__ lz,
                                             int* __restrict__ counts) {
    int t = blockIdx.x;
    int tid = threadIdx.x, wv = tid >> 6, lane = tid & 63;
    int tx = t & 7, ty = t >> 3;
    float x_lo = (float)(2 * (tx * 16) + 1 - IMG) / (float)IMG;
    float x_hi = (float)(2 * (tx * 16 + 15) + 1 - IMG) / (float)IMG;
    float y_hi = (float)(127 - 2 * (ty * 16)) / (float)IMG;
    float y_lo = (float)(127 - 2 * (ty * 16 + 15)) / (float)IMG;
    float cx = 0.5f * (x_lo + x_hi), hx = 0.5f * (x_hi - x_lo);
    float cy = 0.5f * (y_lo + y_hi), hy = 0.5f * (y_hi - y_lo);

    __shared__ int wc[4];
    int cnt = 0;
    for (int base = 0; base < NFACE; base += 256) {
        int j = base + tid;
        bool ov = false;
        float zub = 0.0f;
        if (j < NFACE) {
            const float4* H = (const float4*)(fb2 + (size_t)j * FSTR);
            float4 h0 = H[0], h1 = H[1], h2 = H[2], h3 = H[3];
            ov = (h0.x <= x_hi) & (h0.y >= x_lo) & (h0.z <= y_hi) & (h0.w >= y_lo);
            if (ov) {
                float dx = cx - h1.x, dy = cy - h1.y;
                float mx0 = h1.z * dx + h1.w * dy + fabsf(h1.z) * hx + fabsf(h1.w) * hy;
                float mx1 = h2.x * dx + h2.y * dy + fabsf(h2.x) * hx + fabsf(h2.y) * hy;
                float A2 = -(h1.z + h2.x), B2 = -(h1.w + h2.y);
                float mx2 = h2.z + A2 * dx + B2 * dy + fabsf(A2) * hx + fabsf(B2) * hy;
                ov = (mx0 >= h3.x) & (mx1 >= h3.y) & (mx2 >= h3.z);
                zub = h2.w;
            }
        }
        unsigned long long mask = __ballot(ov);
        if (lane == 0) wc[wv] = __popcll(mask);
        __syncthreads();
        int off = cnt;
        for (int w = 0; w < 4; ++w) {
            if (w < wv) off += wc[w];
        }
        if (ov) {
            int pos = off + __popcll(mask & ((1ull << lane) - 1ull));
            lid[(size_t)t * CAP + pos] = j;
            lz[(size_t)t * CAP + pos] = zub;
        }
        cnt += wc[0] + wc[1] + wc[2] + wc[3];
        __syncthreads();
    }
    if (tid == 0) counts[t] = cnt;
}

// one wave: S_t ~ len_t (sum <= B), prefix starts, block->(tile,seg) map
__global__ __launch_bounds__(64) void k_map(const int* __restrict__ counts,
                                            int* __restrict__ map,
                                            int* __restrict__ starts,
                                            int* __restrict__ segs,
                                            int B) {
    int lane = threadIdx.x;
    int len = counts[lane];
    int tot = len;
    for (int o = 32; o > 0; o >>= 1) tot += __shfl_down(tot, o);
    tot = __shfl(tot, 0);
    int St = max(1, (int)(((long long)len * (long long)(B - NTILE)) /
                          (long long)max(tot, 1)));
    __shared__ int sS[64], sP[64];
    sS[lane] = St;
    __syncthreads();
    if (lane == 0) {
        int acc = 0;
        for (int t = 0; t < 64; ++t) { sP[t] = acc; acc += sS[t]; }
    }
    __syncthreads();
    for (int i = lane; i < B; i += 64) map[i] = -1;
    __syncthreads();
    int st = sP[lane];
    starts[lane] = st;
    segs[lane] = St;
    for (int s = 0; s < St; ++s) map[st + s] = (lane << 16) | s;
}

__global__ __launch_bounds__(256) void k_main(const float* __restrict__ fb2,
                                              const int* __restrict__ lid,
                                              const float* __restrict__ lz,
                                              const int* __restrict__ counts,
                                              const int* __restrict__ map,
                                              const int* __restrict__ segs,
                                              float* __restrict__ part) {
    int bid = blockIdx.x;
    int mv = map[bid];
    if (mv < 0) return;
    int t = mv >> 16, seg = mv & 0xffff;
    int S = segs[t];
    int len = counts[t];

    int tid = threadIdx.x;
    int tx = t & 7, ty = t >> 3;
    int col = tx * 16 + (tid & 15);
    int row = ty * 16 + (tid >> 4);
    float px = (float)(2 * col + 1 - IMG) / (float)IMG;
    float py = (float)(2 * (IMG - 1 - row) + 1 - IMG) / (float)IMG;

    const int*   plid = lid + (size_t)t * CAP;
    const float* plz  = lz  + (size_t)t * CAP;

    float m = -__builtin_inff();
    float s = 0.0f, ca = 0.0f, cb = 0.0f, cc = 0.0f, pr = 1.0f;

    const float NEAR_T = 4.3e-3f;   // lb > this => sigmoid rounds to 1.0f exactly
    const float ZM = 1.3e-4f;       // exp((zpn-m)*1e6) == 0.0f beyond this gap

    int i = seg;
    float zubi = 0.0f; int fj = 0;
    float4 h0, h1, h2, h3;
    if (i < len) {
        zubi = rfl_f(plz[i]);
        fj = __builtin_amdgcn_readfirstlane(plid[i]);
        const float4* H = (const float4*)(fb2 + (size_t)fj * FSTR);
        h0 = H[0]; h1 = H[1]; h2 = H[2]; h3 = H[3];
    }
    while (i < len) {
        // absorbing state: list is zub-desc => rest is a bit-exact no-op
        if (__all((pr == 0.0f) & (zubi <= m - ZM))) break;
        float zcur = zubi;
        int fcur = fj;
        float4 g0 = h0, g1 = h1, g2 = h2, g3 = h3;
        int inext = i + S;
        if (inext < len) {                    // prefetch next entry + head
            zubi = rfl_f(plz[inext]);
            fj = __builtin_amdgcn_readfirstlane(plid[inext]);
            const float4* H = (const float4*)(fb2 + (size_t)fj * FSTR);
            h0 = H[0]; h1 = H[1]; h2 = H[2]; h3 = H[3];
        }
        i = inext;

        bool inbox = (px >= g0.x) & (px <= g0.y) & (py >= g0.z) & (py <= g0.w);
        if (!__any(inbox)) continue;

        float x2 = g1.x, y2 = g1.y;
        float dx2 = px - x2, dy2 = py - y2;
        float num0 = g1.z * dx2 + g1.w * dy2;
        float num1 = g2.x * dx2 + g2.y * dy2;
        float detp = g2.z;
        float num2 = detp - num0 - num1;
        bool maybe = inbox & (num0 >= g3.x) & (num1 >= g3.y) & (num2 >= g3.z);
        if (!__any(maybe)) continue;

        const float* F = fb2 + (size_t)fcur * FSTR;

        bool inside = (num0 >= 0.0f) & (num1 >= 0.0f) & (num2 >= 0.0f);
        bool inside_l = inside & inbox;

        float lin0 = num0 * F[27];
        float lin1 = num1 * F[28];
        float lin2 = num2 * F[29];
        float lbmin = fminf(fminf(lin0, lin1), lin2);

        bool outNear = maybe & (!inside);
        bool nearIn  = inside_l & (lbmin < NEAR_T);
        bool anyNear = __any(nearIn | outNear);

        float dis = 1e9f;
        float Dp;
        if (anyNear) {
            bool needAll = __any(outNear);
            float x0 = F[16], y0 = F[17], x1 = F[18], y1 = F[19];
            float d01 = 1e9f, d12 = 1e9f, d20 = 1e9f;
            if (needAll | __any(inside_l & (lin2 < NEAR_T)))
                d01 = segd(px, py, x0, y0, x1, y1, F[20]);
            if (needAll | __any(inside_l & (lin0 < NEAR_T)))
                d12 = segd(px, py, x1, y1, x2, y2, F[21]);
            if (needAll | __any(inside_l & (lin1 < NEAR_T)))
                d20 = segd(px, py, x2, y2, x0, y0, F[22]);
            dis = fminf(fminf(d01, d12), d20);

            float q = dis * 1e6f;
            float xs_ = inside ? q : -q;
            float tt = __expf(-fabsf(xs_));
            float Dpn = (xs_ >= 0.0f ? 1.0f : tt) * rcp_nr(1.0f + tt);
            bool nearl = nearIn | outNear;
            Dp = nearl ? Dpn : (inside_l ? 1.0f : 0.0f);
        } else {
            Dp = inside_l ? 1.0f : 0.0f;
        }

        bool contrib = inside_l | (outNear & (dis < 1e-10f));
        Dp = contrib ? Dp : 0.0f;
        float omd = 1.0f - Dp;
        pr *= contrib ? (omd * omd) : 1.0f;   // both winding copies

        float multf = g3.w;
        bool doz = contrib & (multf > 0.0f);
        if (__any(doz & (zcur > m - ZM))) {
            float rdetp = F[23];
            float w0 = num0 * rdetp;
            float w1 = num1 * rdetp;
            float c0 = fminf(fmaxf(w0, 0.0f), 1.0f);
            float c1 = fminf(fmaxf(w1, 0.0f), 1.0f);
            float c2 = fminf(fmaxf(1.0f - w0 - w1, 0.0f), 1.0f);
            float csum = fmaxf(c0 + c1 + c2, 1e-5f);
            float rcs = rcp_nr(csum);
            c0 *= rcs; c1 *= rcs; c2 *= rcs;
            float zpi = c0 * F[24] + c1 * F[25] + c2 * F[26];
            if (fabsf(zpi) < 1e-12f) zpi = 1e-12f;
            float zp = rcp_nr(zpi);
            if (doz & (zp >= 1.0f) & (zp <= 100.0f)) {
                float zpn = (100.0f - zp) / 99.0f;   // keep IEEE: critical
                if (zpn > m) {
                    float scl = __expf((m - zpn) * 1e6f);
                    s *= scl; ca *= scl; cb *= scl; cc *= scl;
                    m = zpn;
                }
                float arg = (zpn - m) * 1e6f;
                if (arg > -110.0f) {
                    float e = __expf(arg) * Dp * multf;
                    float col0 = c0 * F[30] + c1 * F[33] + c2 * F[36];
                    float col1 = c0 * F[31] + c1 * F[34] + c2 * F[37];
                    float col2 = c0 * F[32] + c1 * F[35] + c2 * F[38];
                    s += e; ca += e * col0; cb += e * col1; cc += e * col2;
                }
            }
        }
    }

    size_t pb = (size_t)bid * 6 * 256;
    part[pb + 0 * 256 + tid] = m;
    part[pb + 1 * 256 + tid] = s;
    part[pb + 2 * 256 + tid] = ca;
    part[pb + 3 * 256 + tid] = cb;
    part[pb + 4 * 256 + tid] = cc;
    part[pb + 5 * 256 + tid] = pr;
}

__global__ __launch_bounds__(256) void k_reduce(const float* __restrict__ part,
                                                const int* __restrict__ starts,
                                                const int* __restrict__ segs,
                                                float* __restrict__ out) {
    int t = blockIdx.x;
    int q = threadIdx.x;
    int tx = t & 7, ty = t >> 3;
    int col = tx * 16 + (q & 15);
    int row = ty * 16 + (q >> 4);
    int p = row * IMG + col;
    int start = starts[t], S = segs[t];

    float m = 0.001f;   // BG_EPS
    for (int sgi = 0; sgi < S; sgi++)
        m = fmaxf(m, part[((size_t)(start + sgi) * 6 + 0) * 256 + q]);
    float sum = __expf((0.001f - m) * 1e6f);   // background term (s0=1)
    float a = 0.0f, b = 0.0f, c = 0.0f, pr = 1.0f;
    for (int sgi = 0; sgi < S; sgi++) {
        const float* r = part + ((size_t)(start + sgi) * 6) * 256;
        float w = __expf((r[0 * 256 + q] - m) * 1e6f);
        pr *= r[5 * 256 + q];
        if (__any(w != 0.0f)) {
            sum += r[1 * 256 + q] * w;
            a += r[2 * 256 + q] * w;
            b += r[3 * 256 + q] * w;
            c += r[4 * 256 + q] * w;
        }
    }
    out[0 * P_TOT + p] = a / sum;
    out[1 * P_TOT + p] = b / sum;
    out[2 * P_TOT + p] = c / sum;
    out[3 * P_TOT + p] = 1.0f - pr;
}

extern "C" void kernel_launch(void* const* d_in, const int* in_sizes, int n_in,
                              void* d_out, int out_size, void* d_ws, size_t ws_size,
                              hipStream_t stream) {
    const float* verts = (const float*)d_in[0];
    const int*   faces = (const int*)d_in[1];
    const float* attrs = (const float*)d_in[2];
    float* out = (float*)d_out;
    float* ws  = (float*)d_ws;

    float* fb     = ws;                                   // 400k floats
    int*   hist   = (int*)(fb + (size_t)NFACE * FSTR);    // NCH*NB
    float* fb2    = (float*)(hist + NCH * NB);            // 400k floats
    int*   lid    = (int*)(fb2 + (size_t)NFACE * FSTR);   // NTILE*CAP
    float* lz     = (float*)(lid + (size_t)NTILE * CAP);  // NTILE*CAP
    int*   counts = (int*)(lz + (size_t)NTILE * CAP);     // 64
    int*   map    = counts + NTILE;                       // BMAX
    int*   starts = map + BMAX;                           // 64
    int*   segsum = starts + NTILE;                       // 64
    float* part   = (float*)(segsum + NTILE);

    size_t used_f = 2 * (size_t)NFACE * FSTR + NCH * NB
                  + 2 * (size_t)NTILE * CAP + NTILE + BMAX + 2 * NTILE;
    long   rem_f  = (long)(ws_size / 4) - (long)used_f;
    int B = (int)(rem_f / (6 * 256));
    if (B > BMAX) B = BMAX;
    if (B < 256)  B = 256;

    k_prehist<<<NCH, 256, 0, stream>>>(verts, faces, attrs, fb, hist);
    k_scan<<<1, 1024, 0, stream>>>(hist);
    k_scatterre<<<NCH, 256, 0, stream>>>(fb, hist, fb2);
    k_bin<<<NTILE, 256, 0, stream>>>(fb2, lid, lz, counts);
    k_map<<<1, 64, 0, stream>>>(counts, map, starts, segsum, B);
    k_main<<<B, 256, 0, stream>>>(fb2, lid, lz, counts, map, segsum, part);
    k_reduce<<<NTILE, 256, 0, stream>>>(part, starts, segsum, out);
}

// Round 12
// 138.708 us; speedup vs baseline: 2.1253x; 1.3887x over previous
//
#include <hip/hip_runtime.h>
#include <math.h>

// SoftRasterizer: B=1, V=5023, F=10000, IMG=128.
// R12 = R11 with the NaN fix: per-sub k_reduce weight guarded for empty
// segments (mp=-inf & r[0]=-inf gave expf(NaN)). Otherwise identical.
// R11 changes vs R10: k_bin 256 blocks (tile x quarter, z-desc concat),
// SoA float2 tile lists, 1024-thr k_reduce with LDS 4->1 exact merge,
// no head prefetch (issue-bound), B <= 4096 adaptive.
// Eval arithmetic bit-identical to R6-R10 (absmax 3.9e-3).

#define NFACE 10000
#define IMG   128
#define P_TOT (IMG*IMG)
#define FSTR  40
#define NTILE 64               // 8x8 tiles of 16x16 px
#define NQ    4
#define CAPQ  2500             // quarter size (hard bound: 2500 faces/quarter)
#define CAP   (CAPQ*NQ)
#define BMAX  4096
#define NB    1024             // z buckets
#define CH    256
#define NCH   40               // NFACE/CH
#define Z_LO  0.85f
#define Z_W   (0.12f/1024.0f)

__device__ __forceinline__ float rcp_nr(float x) {
    float r = __builtin_amdgcn_rcpf(x);
    r = r * __builtin_fmaf(-x, r, 2.0f);
    return r;
}

__device__ __forceinline__ float segd(float px, float py, float ax, float ay,
                                      float bx, float by, float il) {
    float dx = px - ax, dy = py - ay;
    float ex = bx - ax, ey = by - ay;
    float t = (dx * ex + dy * ey) * il;
    t = fminf(fmaxf(t, 0.0f), 1.0f);
    float rx = dx - t * ex, ry = dy - t * ey;
    return rx * rx + ry * ry;
}

__device__ __forceinline__ float rfl_f(float x) {
    return __uint_as_float(__builtin_amdgcn_readfirstlane(__float_as_uint(x)));
}

__device__ __forceinline__ int zbucket(float zub) {
    int b = (int)((zub - Z_LO) * (1.0f / Z_W));
    return min(max(b, 0), NB - 1);
}

// fused k_pre + k_hist
__global__ __launch_bounds__(256) void k_prehist(const float* __restrict__ v,
                                                 const int* __restrict__ fc,
                                                 const float* __restrict__ at,
                                                 float* __restrict__ fb,
                                                 int* __restrict__ hist) {
    __shared__ int lh[NB];
    int c = blockIdx.x, tid = threadIdx.x;
    for (int j = tid; j < NB; j += 256) lh[j] = 0;
    __syncthreads();

    int f = c * CH + tid;
    if (f < NFACE) {
        int i0 = fc[3 * f], i1 = fc[3 * f + 1], i2 = fc[3 * f + 2];
        float x0 = -v[3 * i0], y0 = v[3 * i0 + 1], z0 = v[3 * i0 + 2];
        float x1 = -v[3 * i1], y1 = v[3 * i1 + 1], z1 = v[3 * i1 + 2];
        float x2 = -v[3 * i2], y2 = v[3 * i2 + 1], z2 = v[3 * i2 + 2];

        float det = (y1 - y2) * (x0 - x2) + (x2 - x1) * (y0 - y2);
        if (fabsf(det) < 1e-10f) det = (det < 0.0f) ? -1e-10f : 1e-10f;
        float a0 = y1 - y2, b0 = x2 - x1, a1 = y2 - y0, b1 = x0 - x2, detp = det;
        if (det < 0.0f) { detp = -det; a0 = -a0; b0 = -b0; a1 = -a1; b1 = -b1; }

        float a2 = a0 + a1, b2 = b0 + b1;
        float g0 = fmaxf(sqrtf(a0 * a0 + b0 * b0), 1e-12f);
        float g1 = fmaxf(sqrtf(a1 * a1 + b1 * b1), 1e-12f);
        float g2 = fmaxf(sqrtf(a2 * a2 + b2 * b2), 1e-12f);
        const float MARG = 3e-5f, AG = 1e-9f;
        float m0 = -(MARG * g0 + AG), m1 = -(MARG * g1 + AG), m2 = -(MARG * g2 + AG);

        float e01x = x1 - x0, e01y = y1 - y0;
        float e12x = x2 - x1, e12y = y2 - y1;
        float e20x = x0 - x2, e20y = y0 - y2;
        float il01 = 1.0f / fmaxf(e01x * e01x + e01y * e01y, 1e-12f);
        float il12 = 1.0f / fmaxf(e12x * e12x + e12y * e12y, 1e-12f);
        float il20 = 1.0f / fmaxf(e20x * e20x + e20y * e20y, 1e-12f);

        const float BM = 2e-5f;
        float bxmin = fminf(fminf(x0, x1), x2) - BM, bxmax = fmaxf(fmaxf(x0, x1), x2) + BM;
        float bymin = fminf(fminf(y0, y1), y2) - BM, bymax = fmaxf(fmaxf(y0, y1), y2) + BM;

        int mult = (((y2 - y0) * (x1 - x0)) < ((y1 - y0) * (x2 - x0)))
                 + (((y0 - y2) * (x1 - x2)) < ((y1 - y2) * (x0 - x2)));

        float zmin = fminf(fminf(z0, z1), z2);
        float zub = (100.0f - zmin) / 99.0f + 2e-6f;

        float* F = fb + (size_t)f * FSTR;
        F[0] = bxmin; F[1] = bxmax; F[2] = bymin; F[3] = bymax;
        F[4] = x2; F[5] = y2; F[6] = a0; F[7] = b0;
        F[8] = a1; F[9] = b1; F[10] = detp; F[11] = zub;
        F[12] = m0; F[13] = m1; F[14] = m2; F[15] = (float)mult;
        F[16] = x0; F[17] = y0; F[18] = x1; F[19] = y1;
        F[20] = il01; F[21] = il12; F[22] = il20; F[23] = 1.0f / detp;
        F[24] = 1.0f / z0; F[25] = 1.0f / z1; F[26] = 1.0f / z2;
        F[27] = 1.0f / g0; F[28] = 1.0f / g1; F[29] = 1.0f / g2;
#pragma unroll
        for (int k = 0; k < 9; k++) F[30 + k] = at[(size_t)f * 9 + k];
        F[39] = 0.0f;

        atomicAdd(&lh[zbucket(zub)], 1);
    }
    __syncthreads();
    for (int j = tid; j < NB; j += 256) hist[c * NB + j] = lh[j];
}

// one block: suffix-sum over buckets (desc) + per-chunk bases in-place
__global__ __launch_bounds__(1024) void k_scan(int* __restrict__ hist) {
    __shared__ int a[NB];
    int t = threadIdx.x;
    int tot = 0;
    for (int c = 0; c < NCH; c++) tot += hist[c * NB + t];
    a[t] = tot;
    for (int off = 1; off < NB; off <<= 1) {
        __syncthreads();
        int v = a[t] + ((t + off < NB) ? a[t + off] : 0);
        __syncthreads();
        a[t] = v;
    }
    int r = a[t] - tot;
    for (int c = 0; c < NCH; c++) {
        int h = hist[c * NB + t];
        hist[c * NB + t] = r;
        r += h;
    }
}

// scatter + physical reorder: fb2[pos] = fb[f], F[11] := bucket upper bound
__global__ __launch_bounds__(256) void k_scatterre(const float* __restrict__ fb,
                                                   const int* __restrict__ hist,
                                                   float* __restrict__ fb2) {
    __shared__ int sb[CH];
    int c = blockIdx.x, tid = threadIdx.x;
    int f = c * CH + tid;
    bool valid = (f < NFACE);
    int b = valid ? zbucket(fb[(size_t)f * FSTR + 11]) : -1;
    sb[tid] = b;
    __syncthreads();
    if (valid) {
        int rank = 0;
        for (int j = 0; j < CH; j++) {
            int v2 = sb[j];
            rank += (j < tid && v2 == b) ? 1 : 0;
        }
        int pos = hist[c * NB + b] + rank;
        const float4* src = (const float4*)(fb + (size_t)f * FSTR);
        float4* dst = (float4*)(fb2 + (size_t)pos * FSTR);
#pragma unroll
        for (int k = 0; k < 10; k++) dst[k] = src[k];
        fb2[(size_t)pos * FSTR + 11] = Z_LO + (float)(b + 1) * Z_W + 1e-7f;
    }
}

// 256 blocks: (tile, quarter). Quarter q = z-desc rows [q*CAPQ,(q+1)*CAPQ).
__global__ __launch_bounds__(256) void k_bin(const float* __restrict__ fb2,
                                             float2* __restrict__ tmeta,
                                             int* __restrict__ cnt4) {
    int t = blockIdx.x >> 2, q = blockIdx.x & 3;
    int tid = threadIdx.x, wv = tid >> 6, lane = tid & 63;
    int tx = t & 7, ty = t >> 3;
    float x_lo = (float)(2 * (tx * 16) + 1 - IMG) / (float)IMG;
    float x_hi = (float)(2 * (tx * 16 + 15) + 1 - IMG) / (float)IMG;
    float y_hi = (float)(127 - 2 * (ty * 16)) / (float)IMG;
    float y_lo = (float)(127 - 2 * (ty * 16 + 15)) / (float)IMG;
    float cx = 0.5f * (x_lo + x_hi), hx = 0.5f * (x_hi - x_lo);
    float cy = 0.5f * (y_lo + y_hi), hy = 0.5f * (y_hi - y_lo);

    __shared__ int wc[4];
    int cnt = 0;
    int f0 = q * CAPQ;
    for (int base = f0; base < f0 + CAPQ; base += 256) {
        int j = base + tid;
        bool ov = false;
        float zub = 0.0f;
        if (j < f0 + CAPQ) {
            const float4* H = (const float4*)(fb2 + (size_t)j * FSTR);
            float4 h0 = H[0], h1 = H[1], h2 = H[2], h3 = H[3];
            ov = (h0.x <= x_hi) & (h0.y >= x_lo) & (h0.z <= y_hi) & (h0.w >= y_lo);
            if (ov) {
                float dx = cx - h1.x, dy = cy - h1.y;
                float mx0 = h1.z * dx + h1.w * dy + fabsf(h1.z) * hx + fabsf(h1.w) * hy;
                float mx1 = h2.x * dx + h2.y * dy + fabsf(h2.x) * hx + fabsf(h2.y) * hy;
                float A2 = -(h1.z + h2.x), B2 = -(h1.w + h2.y);
                float mx2 = h2.z + A2 * dx + B2 * dy + fabsf(A2) * hx + fabsf(B2) * hy;
                ov = (mx0 >= h3.x) & (mx1 >= h3.y) & (mx2 >= h3.z);
                zub = h2.w;
            }
        }
        unsigned long long mask = __ballot(ov);
        if (lane == 0) wc[wv] = __popcll(mask);
        __syncthreads();
        int off = cnt;
        for (int w = 0; w < 4; ++w) {
            if (w < wv) off += wc[w];
        }
        if (ov) {
            int pos = off + __popcll(mask & ((1ull << lane) - 1ull));
            tmeta[(size_t)t * CAP + q * CAPQ + pos] =
                make_float2(zub, __int_as_float(j));
        }
        cnt += wc[0] + wc[1] + wc[2] + wc[3];
        __syncthreads();
    }
    if (tid == 0) cnt4[t * 4 + q] = cnt;
}

// one wave: S_t ~ len_t (sum <= B), prefix starts, block->(tile,seg) map
__global__ __launch_bounds__(64) void k_map(const int* __restrict__ cnt4,
                                            int* __restrict__ map,
                                            int* __restrict__ starts,
                                            int* __restrict__ segs,
                                            int B) {
    int lane = threadIdx.x;
    int len = cnt4[4 * lane] + cnt4[4 * lane + 1] + cnt4[4 * lane + 2] + cnt4[4 * lane + 3];
    int tot = len;
    for (int o = 32; o > 0; o >>= 1) tot += __shfl_down(tot, o);
    tot = __shfl(tot, 0);
    int St = max(1, (int)(((long long)len * (long long)(B - NTILE)) /
                          (long long)max(tot, 1)));
    __shared__ int sS[64], sP[64];
    sS[lane] = St;
    __syncthreads();
    if (lane == 0) {
        int acc = 0;
        for (int t = 0; t < 64; ++t) { sP[t] = acc; acc += sS[t]; }
    }
    __syncthreads();
    for (int i = lane; i < B; i += 64) map[i] = -1;
    __syncthreads();
    int st = sP[lane];
    starts[lane] = st;
    segs[lane] = St;
    for (int s = 0; s < St; ++s) map[st + s] = (lane << 16) | s;
}

__global__ __launch_bounds__(256) void k_main(const float* __restrict__ fb2,
                                              const float2* __restrict__ tmeta,
                                              const int* __restrict__ cnt4,
                                              const int* __restrict__ map,
                                              const int* __restrict__ segs,
                                              float* __restrict__ part) {
    int bid = blockIdx.x;
    int mv = map[bid];
    if (mv < 0) return;
    int t = mv >> 16, seg = mv & 0xffff;
    int S = segs[t];

    int tid = threadIdx.x;
    int tx = t & 7, ty = t >> 3;
    int col = tx * 16 + (tid & 15);
    int row = ty * 16 + (tid >> 4);
    float px = (float)(2 * col + 1 - IMG) / (float)IMG;
    float py = (float)(2 * (IMG - 1 - row) + 1 - IMG) / (float)IMG;

    const float2* pm = tmeta + (size_t)t * CAP;

    float m = -__builtin_inff();
    float s = 0.0f, ca = 0.0f, cb = 0.0f, cc = 0.0f, pr = 1.0f;

    const float NEAR_T = 4.3e-3f;   // lb > this => sigmoid rounds to 1.0f exactly
    const float ZM = 1.3e-4f;       // exp((zpn-m)*1e6) == 0.0f beyond this gap

    bool done = false;
    for (int q = 0; q < 4 && !done; ++q) {
        int qlen = cnt4[t * 4 + q];
        for (int i = seg; i < qlen; i += S) {
            float2 mt = pm[q * CAPQ + i];
            float zcur = rfl_f(mt.x);
            // absorbing state: list is zub-desc globally => rest is no-op
            if (__all((pr == 0.0f) & (zcur <= m - ZM))) { done = true; break; }
            int fj = __builtin_amdgcn_readfirstlane(__float_as_int(mt.y));
            const float4* H = (const float4*)(fb2 + (size_t)fj * FSTR);
            float4 g0 = H[0], g1 = H[1], g2 = H[2], g3 = H[3];

            bool inbox = (px >= g0.x) & (px <= g0.y) & (py >= g0.z) & (py <= g0.w);
            if (!__any(inbox)) continue;

            float x2 = g1.x, y2 = g1.y;
            float dx2 = px - x2, dy2 = py - y2;
            float num0 = g1.z * dx2 + g1.w * dy2;
            float num1 = g2.x * dx2 + g2.y * dy2;
            float detp = g2.z;
            float num2 = detp - num0 - num1;
            bool maybe = inbox & (num0 >= g3.x) & (num1 >= g3.y) & (num2 >= g3.z);
            if (!__any(maybe)) continue;

            const float* F = fb2 + (size_t)fj * FSTR;

            bool inside = (num0 >= 0.0f) & (num1 >= 0.0f) & (num2 >= 0.0f);
            bool inside_l = inside & inbox;

            float lin0 = num0 * F[27];
            float lin1 = num1 * F[28];
            float lin2 = num2 * F[29];
            float lbmin = fminf(fminf(lin0, lin1), lin2);

            bool outNear = maybe & (!inside);
            bool nearIn  = inside_l & (lbmin < NEAR_T);
            bool anyNear = __any(nearIn | outNear);

            float dis = 1e9f;
            float Dp;
            if (anyNear) {
                bool needAll = __any(outNear);
                float x0 = F[16], y0 = F[17], x1 = F[18], y1 = F[19];
                float d01 = 1e9f, d12 = 1e9f, d20 = 1e9f;
                if (needAll | __any(inside_l & (lin2 < NEAR_T)))
                    d01 = segd(px, py, x0, y0, x1, y1, F[20]);
                if (needAll | __any(inside_l & (lin0 < NEAR_T)))
                    d12 = segd(px, py, x1, y1, x2, y2, F[21]);
                if (needAll | __any(inside_l & (lin1 < NEAR_T)))
                    d20 = segd(px, py, x2, y2, x0, y0, F[22]);
                dis = fminf(fminf(d01, d12), d20);

                float qq = dis * 1e6f;
                float xs_ = inside ? qq : -qq;
                float tt = __expf(-fabsf(xs_));
                float Dpn = (xs_ >= 0.0f ? 1.0f : tt) * rcp_nr(1.0f + tt);
                bool nearl = nearIn | outNear;
                Dp = nearl ? Dpn : (inside_l ? 1.0f : 0.0f);
            } else {
                Dp = inside_l ? 1.0f : 0.0f;
            }

            bool contrib = inside_l | (outNear & (dis < 1e-10f));
            Dp = contrib ? Dp : 0.0f;
            float omd = 1.0f - Dp;
            pr *= contrib ? (omd * omd) : 1.0f;   // both winding copies

            float multf = g3.w;
            bool doz = contrib & (multf > 0.0f);
            if (__any(doz & (zcur > m - ZM))) {
                float rdetp = F[23];
                float w0 = num0 * rdetp;
                float w1 = num1 * rdetp;
                float c0 = fminf(fmaxf(w0, 0.0f), 1.0f);
                float c1 = fminf(fmaxf(w1, 0.0f), 1.0f);
                float c2 = fminf(fmaxf(1.0f - w0 - w1, 0.0f), 1.0f);
                float csum = fmaxf(c0 + c1 + c2, 1e-5f);
                float rcs = rcp_nr(csum);
                c0 *= rcs; c1 *= rcs; c2 *= rcs;
                float zpi = c0 * F[24] + c1 * F[25] + c2 * F[26];
                if (fabsf(zpi) < 1e-12f) zpi = 1e-12f;
                float zp = rcp_nr(zpi);
                if (doz & (zp >= 1.0f) & (zp <= 100.0f)) {
                    float zpn = (100.0f - zp) / 99.0f;   // keep IEEE: critical
                    if (zpn > m) {
                        float scl = __expf((m - zpn) * 1e6f);
                        s *= scl; ca *= scl; cb *= scl; cc *= scl;
                        m = zpn;
                    }
                    float arg = (zpn - m) * 1e6f;
                    if (arg > -110.0f) {
                        float e = __expf(arg) * Dp * multf;
                        float col0 = c0 * F[30] + c1 * F[33] + c2 * F[36];
                        float col1 = c0 * F[31] + c1 * F[34] + c2 * F[37];
                        float col2 = c0 * F[32] + c1 * F[35] + c2 * F[38];
                        s += e; ca += e * col0; cb += e * col1; cc += e * col2;
                    }
                }
            }
        }
    }

    size_t pb = (size_t)bid * 6 * 256;
    part[pb + 0 * 256 + tid] = m;
    part[pb + 1 * 256 + tid] = s;
    part[pb + 2 * 256 + tid] = ca;
    part[pb + 3 * 256 + tid] = cb;
    part[pb + 4 * 256 + tid] = cc;
    part[pb + 5 * 256 + tid] = pr;
}

// 1024 threads: 4 subs x 256 px; exact online-softmax 4->1 LDS merge
__global__ __launch_bounds__(1024) void k_reduce(const float* __restrict__ part,
                                                 const int* __restrict__ starts,
                                                 const int* __restrict__ segs,
                                                 float* __restrict__ out) {
    __shared__ float sm[4][256], ss[4][256], sa[4][256], sb2[4][256],
                     sc[4][256], sp[4][256];
    int t = blockIdx.x;
    int tid = threadIdx.x;
    int q = tid & 255, sub = tid >> 8;
    int start = starts[t], S = segs[t];

    const float NINF = -__builtin_inff();
    float mp = NINF;
    for (int sgi = sub; sgi < S; sgi += 4)
        mp = fmaxf(mp, part[((size_t)(start + sgi) * 6 + 0) * 256 + q]);
    float sum = 0.0f, a = 0.0f, b = 0.0f, c = 0.0f, pr = 1.0f;
    for (int sgi = sub; sgi < S; sgi += 4) {
        const float* r = part + ((size_t)(start + sgi) * 6) * 256;
        float rm = r[0 * 256 + q];
        // guard: rm=-inf & mp=-inf would give expf(NaN); empty seg => weight 0
        float w = (rm == NINF) ? 0.0f : __expf((rm - mp) * 1e6f);
        pr *= r[5 * 256 + q];
        if (__any(w != 0.0f)) {
            sum += r[1 * 256 + q] * w;
            a += r[2 * 256 + q] * w;
            b += r[3 * 256 + q] * w;
            c += r[4 * 256 + q] * w;
        }
    }
    sm[sub][q] = mp; ss[sub][q] = sum; sa[sub][q] = a;
    sb2[sub][q] = b; sc[sub][q] = c;  sp[sub][q] = pr;
    __syncthreads();
    if (sub == 0) {
        int tx = t & 7, ty = t >> 3;
        int col = tx * 16 + (q & 15);
        int row = ty * 16 + (q >> 4);
        int p = row * IMG + col;
        float M = 0.001f;   // BG_EPS
#pragma unroll
        for (int k = 0; k < 4; k++) M = fmaxf(M, sm[k][q]);
        float SUM = __expf((0.001f - M) * 1e6f);   // background (s0=1); M finite
        float A = 0.0f, B2 = 0.0f, C = 0.0f, PR = 1.0f;
#pragma unroll
        for (int k = 0; k < 4; k++) {
            float w = __expf((sm[k][q] - M) * 1e6f);   // sm=-inf -> 0 (M finite)
            SUM += ss[k][q] * w;
            A += sa[k][q] * w;
            B2 += sb2[k][q] * w;
            C += sc[k][q] * w;
            PR *= sp[k][q];
        }
        out[0 * P_TOT + p] = A / SUM;
        out[1 * P_TOT + p] = B2 / SUM;
        out[2 * P_TOT + p] = C / SUM;
        out[3 * P_TOT + p] = 1.0f - PR;
    }
}

extern "C" void kernel_launch(void* const* d_in, const int* in_sizes, int n_in,
                              void* d_out, int out_size, void* d_ws, size_t ws_size,
                              hipStream_t stream) {
    const float* verts = (const float*)d_in[0];
    const int*   faces = (const int*)d_in[1];
    const float* attrs = (const float*)d_in[2];
    float* out = (float*)d_out;
    float* ws  = (float*)d_ws;

    float*  fb    = ws;                                    // 400k floats
    int*    hist  = (int*)(fb + (size_t)NFACE * FSTR);     // NCH*NB
    float*  fb2   = (float*)(hist + NCH * NB);             // 400k floats
    float2* tmeta = (float2*)(fb2 + (size_t)NFACE * FSTR); // NTILE*CAP float2
    int*    cnt4  = (int*)(tmeta + (size_t)NTILE * CAP);   // 256
    int*    map   = cnt4 + NTILE * 4;                      // BMAX
    int*    starts= map + BMAX;                            // 64
    int*    segs  = starts + NTILE;                        // 64
    float*  part  = (float*)(segs + NTILE);

    size_t used_f = 2 * (size_t)NFACE * FSTR + NCH * NB
                  + 2 * (size_t)NTILE * CAP + NTILE * 4 + BMAX + 2 * NTILE;
    long   rem_f  = (long)(ws_size / 4) - (long)used_f;
    int B = (int)(rem_f / (6 * 256));
    if (B > BMAX) B = BMAX;
    if (B < 256)  B = 256;

    k_prehist<<<NCH, 256, 0, stream>>>(verts, faces, attrs, fb, hist);
    k_scan<<<1, 1024, 0, stream>>>(hist);
    k_scatterre<<<NCH, 256, 0, stream>>>(fb, hist, fb2);
    k_bin<<<NTILE * NQ, 256, 0, stream>>>(fb2, tmeta, cnt4);
    k_map<<<1, 64, 0, stream>>>(cnt4, map, starts, segs, B);
    k_main<<<B, 256, 0, stream>>>(fb2, tmeta, cnt4, map, segs, part);
    k_reduce<<<NTILE, 1024, 0, stream>>>(part, starts, segs, out);
}